// Round 3
// baseline (256.388 us; speedup 1.0000x reference)
//
#include <hip/hip_runtime.h>
#include <stdint.h>

typedef short short8 __attribute__((ext_vector_type(8)));
typedef float f32x4 __attribute__((ext_vector_type(4)));

__device__ __forceinline__ float bf2f(unsigned short u) {
    union { unsigned int i; float f; } v; v.i = ((unsigned int)u) << 16; return v.f;
}
__device__ __forceinline__ unsigned short f2bf(float f) {
    union { float f; unsigned int i; } v; v.f = f;
    unsigned int u = v.i;
    unsigned int r = (u + 0x7fffu + ((u >> 16) & 1u)) >> 16;
    return (unsigned short)r;
}

// ---------------- kernel 0: weight transpose (f32 -> bf16 hi, + lo for f/g) -
// wTh[320][256]; wTl[64][256] (lo part only for f,g columns)
__global__ void k_wtrans(const float* __restrict__ Wf,
                         const float* __restrict__ Wg,
                         const float* __restrict__ Wh,
                         unsigned short* __restrict__ wTh,
                         unsigned short* __restrict__ wTl) {
    int col = blockIdx.x;   // 0..319 (output column)
    int k = threadIdx.x;    // 0..255 (input channel)
    float v;
    if (col < 32) v = Wf[k * 32 + col];
    else if (col < 64) v = Wg[k * 32 + (col - 32)];
    else v = Wh[k * 256 + (col - 64)];
    unsigned short h = f2bf(v);
    wTh[col * 256 + k] = h;
    if (col < 64) wTl[col * 256 + k] = f2bf(v - bf2f(h));
}

// ---------------- kernel 1a: f,g projection, 3-term split GEMM -------------
// [16384 x 64] = x[16384 x 256] @ W[256 x 64], fp32-quality via
// x_hi*W_hi + x_lo*W_hi + x_hi*W_lo. Output stored as bf16 hi/lo pairs.
__global__ __launch_bounds__(256) void k_projfg(
    const float* __restrict__ x,
    const unsigned short* __restrict__ wTh,
    const unsigned short* __restrict__ wTl,
    const float* __restrict__ bfb,
    const float* __restrict__ bgb,
    unsigned short* __restrict__ fKh,
    unsigned short* __restrict__ fKl,
    unsigned short* __restrict__ gQh,
    unsigned short* __restrict__ gQl) {
    __shared__ short sm[4 * 64 * 72];   // XH, XL, WH, WL tiles [64][64->72]
    const int XH = 0, XL = 64 * 72, WH = 2 * 64 * 72, WL = 3 * 64 * 72;
    int tid = threadIdx.x;
    int wave = tid >> 6, lane = tid & 63, lq = lane & 15, quad = lane >> 4;
    int rt = blockIdx.x;   // row tile 0..255
    const float* xbase = x + (size_t)rt * 64 * 256;

    f32x4 zero4 = {0.f, 0.f, 0.f, 0.f};
    f32x4 acc[4] = {zero4, zero4, zero4, zero4};

    for (int ph = 0; ph < 4; ++ph) {
        int k0 = ph * 64;
        __syncthreads();
#pragma unroll
        for (int u = 0; u < 2; ++u) {
            int q = u * 256 + tid;          // 0..511 chunks of 8 elems
            int row = q >> 3, kc = q & 7;
            const float* src = &xbase[row * 256 + k0 + kc * 8];
            f32x4 a0 = *(const f32x4*)src;
            f32x4 a1 = *(const f32x4*)(src + 4);
            short8 sh, sl;
#pragma unroll
            for (int j = 0; j < 4; ++j) {
                unsigned short h0 = f2bf(a0[j]);
                sh[j] = (short)h0; sl[j] = (short)f2bf(a0[j] - bf2f(h0));
                unsigned short h1 = f2bf(a1[j]);
                sh[4 + j] = (short)h1; sl[4 + j] = (short)f2bf(a1[j] - bf2f(h1));
            }
            *(short8*)&sm[XH + row * 72 + kc * 8] = sh;
            *(short8*)&sm[XL + row * 72 + kc * 8] = sl;
            *(short8*)&sm[WH + row * 72 + kc * 8] =
                *(const short8*)&wTh[row * 256 + k0 + kc * 8];
            *(short8*)&sm[WL + row * 72 + kc * 8] =
                *(const short8*)&wTl[row * 256 + k0 + kc * 8];
        }
        __syncthreads();
#pragma unroll
        for (int ks = 0; ks < 2; ++ks) {
            short8 ah = *(const short8*)&sm[XH + (wave * 16 + lq) * 72 + ks * 32 + quad * 8];
            short8 al = *(const short8*)&sm[XL + (wave * 16 + lq) * 72 + ks * 32 + quad * 8];
#pragma unroll
            for (int ct = 0; ct < 4; ++ct) {
                short8 bh = *(const short8*)&sm[WH + (lq + 16 * ct) * 72 + ks * 32 + quad * 8];
                short8 bl = *(const short8*)&sm[WL + (lq + 16 * ct) * 72 + ks * 32 + quad * 8];
                acc[ct] = __builtin_amdgcn_mfma_f32_16x16x32_bf16(ah, bh, acc[ct], 0, 0, 0);
                acc[ct] = __builtin_amdgcn_mfma_f32_16x16x32_bf16(al, bh, acc[ct], 0, 0, 0);
                acc[ct] = __builtin_amdgcn_mfma_f32_16x16x32_bf16(ah, bl, acc[ct], 0, 0, 0);
            }
        }
    }

    int rowl = wave * 16 + quad * 4;
#pragma unroll
    for (int ct = 0; ct < 4; ++ct) {
        int coll = lq + 16 * ct;
#pragma unroll
        for (int r = 0; r < 4; ++r) {
            int grow = rt * 64 + rowl + r;
            int bidx = grow >> 12, n = grow & 4095;
            float v = acc[ct][r];
            size_t o = (size_t)(bidx * 4096 + n) * 32;
            if (coll < 32) {
                v += bfb[coll];
                unsigned short h = f2bf(v);
                fKh[o + coll] = h;
                fKl[o + coll] = f2bf(v - bf2f(h));
            } else {
                v += bgb[coll - 32];
                unsigned short h = f2bf(v);
                gQh[o + (coll - 32)] = h;
                gQl[o + (coll - 32)] = f2bf(v - bf2f(h));
            }
        }
    }
}

// ---------------- kernel 1b: h projection GEMM -----------------------------
// hT[B][256][4096] = (x @ Wh + bh) transposed. bf16 single precision.
__global__ __launch_bounds__(256) void k_projh(
    const float* __restrict__ x,
    const unsigned short* __restrict__ wTh,
    const float* __restrict__ bhb,
    unsigned short* __restrict__ hT) {
    __shared__ short sm[2 * 64 * 136];   // rows padded 128->136 elems
    const int XO = 0, WO = 64 * 136;
    int tid = threadIdx.x;
    int wave = tid >> 6, lane = tid & 63, lq = lane & 15, quad = lane >> 4;
    int rt = blockIdx.x;   // row tile 0..255
    int cb = blockIdx.y;   // col block 0..3 (h cols cb*64..+64)
    const float* xbase = x + (size_t)rt * 64 * 256;
    const unsigned short* wbase = wTh + (size_t)(64 + cb * 64) * 256;

    f32x4 zero4 = {0.f, 0.f, 0.f, 0.f};
    f32x4 acc[4] = {zero4, zero4, zero4, zero4};

    for (int ph = 0; ph < 2; ++ph) {
        int k0 = ph * 128;
        __syncthreads();
#pragma unroll
        for (int u = 0; u < 4; ++u) {
            int q = u * 256 + tid;            // 0..1023 chunks of 8 elems
            int row = q >> 4, kc = q & 15;
            const float* src = &xbase[row * 256 + k0 + kc * 8];
            f32x4 a0 = *(const f32x4*)src;
            f32x4 a1 = *(const f32x4*)(src + 4);
            short8 s;
            s[0] = (short)f2bf(a0[0]); s[1] = (short)f2bf(a0[1]);
            s[2] = (short)f2bf(a0[2]); s[3] = (short)f2bf(a0[3]);
            s[4] = (short)f2bf(a1[0]); s[5] = (short)f2bf(a1[1]);
            s[6] = (short)f2bf(a1[2]); s[7] = (short)f2bf(a1[3]);
            *(short8*)&sm[XO + row * 136 + kc * 8] = s;
            *(short8*)&sm[WO + row * 136 + kc * 8] =
                *(const short8*)&wbase[row * 256 + k0 + kc * 8];
        }
        __syncthreads();
#pragma unroll
        for (int ks = 0; ks < 4; ++ks) {
            short8 a = *(const short8*)&sm[XO + (wave * 16 + lq) * 136 + ks * 32 + quad * 8];
#pragma unroll
            for (int ct = 0; ct < 4; ++ct) {
                short8 b = *(const short8*)&sm[WO + (lq + 16 * ct) * 136 + ks * 32 + quad * 8];
                acc[ct] = __builtin_amdgcn_mfma_f32_16x16x32_bf16(a, b, acc[ct], 0, 0, 0);
            }
        }
    }

    int rowl = wave * 16 + quad * 4;
#pragma unroll
    for (int ct = 0; ct < 4; ++ct) {
        int c = cb * 64 + lq + 16 * ct;
#pragma unroll
        for (int r = 0; r < 4; ++r) {
            int grow = rt * 64 + rowl + r;
            int bidx = grow >> 12, n = grow & 4095;
            float v = acc[ct][r] + bhb[c];
            hT[((size_t)bidx * 256 + c) * 4096 + n] = f2bf(v);
        }
    }
}

// ---------------- kernel 2: flash attention --------------------------------
// Grid 512 = B(4) x 128 q-tiles of 32 rows. 4 waves:
//   waves 0,1: S = g.f^T via 3-term hi/lo split + online softmax -> P (bf16)
//   all waves: PV, wave w handles rows (w&1)*16, col half (w>>1)*128
#define HO 0                              // hT tile [256][72]
#define FHO (256 * 72)                    // f_hi tile [64][40]
#define FLO (256 * 72 + 64 * 40)          // f_lo tile [64][40]
#define PO (256 * 72 + 2 * 64 * 40)       // P [2][16][72]
#define SMTOT (256 * 72 + 2 * 64 * 40 + 2 * 16 * 72)

__global__ __launch_bounds__(256) void k_attn(
    const float* __restrict__ x,
    const float* __restrict__ gam_p,
    const unsigned short* __restrict__ fKh,
    const unsigned short* __restrict__ fKl,
    const unsigned short* __restrict__ gQh,
    const unsigned short* __restrict__ gQl,
    const unsigned short* __restrict__ hT,
    float* __restrict__ out) {
    __shared__ short sm[SMTOT];
    __shared__ float af[32];
    __shared__ float lf[32];
    int tid = threadIdx.x;
    int wave = tid >> 6, lane = tid & 63, lq = lane & 15, quad = lane >> 4;
    int b = blockIdx.x >> 7, qt = blockIdx.x & 127;
    int qbase = qt * 32;
    int rb = wave & 1, ch = wave >> 1;

    f32x4 zero4 = {0.f, 0.f, 0.f, 0.f};
    f32x4 acc[8] = {zero4, zero4, zero4, zero4, zero4, zero4, zero4, zero4};
    float m_i[4] = {-1e30f, -1e30f, -1e30f, -1e30f};
    float l_i[4] = {0.f, 0.f, 0.f, 0.f};

    short8 ghfrag = {}, glfrag = {};
    if (wave < 2) {
        size_t go = ((size_t)(b * 4096 + qbase + wave * 16 + lq)) * 32 + quad * 8;
        ghfrag = *(const short8*)&gQh[go];
        glfrag = *(const short8*)&gQl[go];
    }

    for (int kt = 0; kt < 64; ++kt) {
        int kbase = kt * 64;
        __syncthreads();
        // stage f tiles (hi+lo): 64 keys x 32 (4KB contiguous each)
        {
            int row = tid >> 2, kc = tid & 3;
            size_t go = ((size_t)(b * 4096 + kbase)) * 32 + tid * 8;
            *(short8*)&sm[FHO + row * 40 + kc * 8] = *(const short8*)&fKh[go];
            *(short8*)&sm[FLO + row * 40 + kc * 8] = *(const short8*)&fKl[go];
        }
        // stage hT tile: 256 c-rows x 64 keys (rows 128B contiguous)
#pragma unroll
        for (int p = 0; p < 8; ++p) {
            int q = p * 256 + tid;
            int c = q >> 3, kc = q & 7;
            *(short8*)&sm[HO + c * 72 + kc * 8] =
                *(const short8*)&hT[((size_t)b * 256 + c) * 4096 + kbase + kc * 8];
        }
        __syncthreads();

        if (wave < 2) {
            f32x4 S[4];
#pragma unroll
            for (int t = 0; t < 4; ++t) {
                short8 fh = *(const short8*)&sm[FHO + (lq + 16 * t) * 40 + quad * 8];
                short8 fl = *(const short8*)&sm[FLO + (lq + 16 * t) * 40 + quad * 8];
                S[t] = __builtin_amdgcn_mfma_f32_16x16x32_bf16(ghfrag, fh, zero4, 0, 0, 0);
                S[t] = __builtin_amdgcn_mfma_f32_16x16x32_bf16(glfrag, fh, S[t], 0, 0, 0);
                S[t] = __builtin_amdgcn_mfma_f32_16x16x32_bf16(ghfrag, fl, S[t], 0, 0, 0);
            }
            float mn[4], al[4];
#pragma unroll
            for (int r = 0; r < 4; ++r) {
                float mr = fmaxf(fmaxf(S[0][r], S[1][r]), fmaxf(S[2][r], S[3][r]));
                mr = fmaxf(mr, __shfl_xor(mr, 1));
                mr = fmaxf(mr, __shfl_xor(mr, 2));
                mr = fmaxf(mr, __shfl_xor(mr, 4));
                mr = fmaxf(mr, __shfl_xor(mr, 8));
                mn[r] = fmaxf(m_i[r], mr);
                al[r] = __expf(m_i[r] - mn[r]);
                m_i[r] = mn[r];
            }
#pragma unroll
            for (int t = 0; t < 4; ++t)
#pragma unroll
                for (int r = 0; r < 4; ++r) S[t][r] = __expf(S[t][r] - mn[r]);
#pragma unroll
            for (int r = 0; r < 4; ++r) {
                float s = S[0][r] + S[1][r] + S[2][r] + S[3][r];
                s += __shfl_xor(s, 1);
                s += __shfl_xor(s, 2);
                s += __shfl_xor(s, 4);
                s += __shfl_xor(s, 8);
                l_i[r] = l_i[r] * al[r] + s;
            }
            // write P in bf16, [16 rows][64 keys] (row stride 72)
#pragma unroll
            for (int t = 0; t < 4; ++t)
#pragma unroll
                for (int r = 0; r < 4; ++r)
                    sm[PO + wave * 1152 + (quad * 4 + r) * 72 + lq + 16 * t] =
                        (short)f2bf(S[t][r]);
            if (lq == 0) {
#pragma unroll
                for (int r = 0; r < 4; ++r) af[wave * 16 + quad * 4 + r] = al[r];
            }
        }
        __syncthreads();

        // PV phase (all 4 waves)
        float al[4];
        bool sk = true;
#pragma unroll
        for (int r = 0; r < 4; ++r) {
            al[r] = af[rb * 16 + quad * 4 + r];
            sk = sk && (al[r] == 1.0f);
        }
        if (!__all((int)sk)) {
#pragma unroll
            for (int ct = 0; ct < 8; ++ct)
#pragma unroll
                for (int r = 0; r < 4; ++r) acc[ct][r] *= al[r];
        }
        short8 pa0 = *(const short8*)&sm[PO + rb * 1152 + lq * 72 + quad * 8];
        short8 pa1 = *(const short8*)&sm[PO + rb * 1152 + lq * 72 + 32 + quad * 8];
#pragma unroll
        for (int ct = 0; ct < 8; ++ct) {
            int c = lq + 16 * (ch * 8 + ct);
            short8 hb0 = *(const short8*)&sm[HO + c * 72 + quad * 8];
            short8 hb1 = *(const short8*)&sm[HO + c * 72 + 32 + quad * 8];
            acc[ct] = __builtin_amdgcn_mfma_f32_16x16x32_bf16(pa0, hb0, acc[ct], 0, 0, 0);
            acc[ct] = __builtin_amdgcn_mfma_f32_16x16x32_bf16(pa1, hb1, acc[ct], 0, 0, 0);
        }
    }

    if (wave < 2 && lq == 0) {
#pragma unroll
        for (int r = 0; r < 4; ++r) lf[wave * 16 + quad * 4 + r] = l_i[r];
    }
    __syncthreads();

    float gam = gam_p[0];
    float linv[4];
#pragma unroll
    for (int r = 0; r < 4; ++r) linv[r] = 1.0f / lf[rb * 16 + quad * 4 + r];
#pragma unroll
    for (int ct = 0; ct < 8; ++ct) {
        int c = lq + 16 * (ch * 8 + ct);
#pragma unroll
        for (int r = 0; r < 4; ++r) {
            int n = qbase + rb * 16 + quad * 4 + r;
            size_t idx = ((size_t)(b * 4096 + n)) * 256 + c;
            out[idx] = gam * (acc[ct][r] * linv[r]) + x[idx];
        }
    }
}

extern "C" void kernel_launch(void* const* d_in, const int* in_sizes, int n_in,
                              void* d_out, int out_size, void* d_ws, size_t ws_size,
                              hipStream_t stream) {
    const float* x   = (const float*)d_in[0];
    const float* Wf  = (const float*)d_in[1];
    const float* bfb = (const float*)d_in[2];
    const float* Wg  = (const float*)d_in[3];
    const float* bgb = (const float*)d_in[4];
    const float* Wh  = (const float*)d_in[5];
    const float* bhb = (const float*)d_in[6];
    const float* gam = (const float*)d_in[7];
    float* out = (float*)d_out;

    char* ws = (char*)d_ws;
    unsigned short* fKh = (unsigned short*)(ws);                          // 1 MB
    unsigned short* fKl = (unsigned short*)(ws + (1u << 20));             // 1 MB
    unsigned short* gQh = (unsigned short*)(ws + (2u << 20));             // 1 MB
    unsigned short* gQl = (unsigned short*)(ws + (3u << 20));             // 1 MB
    unsigned short* hT  = (unsigned short*)(ws + (4u << 20));             // 8 MB
    unsigned short* wTh = (unsigned short*)(ws + (12u << 20));            // 160 KB
    unsigned short* wTl = (unsigned short*)(ws + (12u << 20) + (256u << 10)); // 32 KB

    k_wtrans<<<dim3(320), dim3(256), 0, stream>>>(Wf, Wg, Wh, wTh, wTl);
    k_projfg<<<dim3(256), dim3(256), 0, stream>>>(x, wTh, wTl, bfb, bgb,
                                                  fKh, fKl, gQh, gQl);
    k_projh<<<dim3(256, 4), dim3(256), 0, stream>>>(x, wTh, bhb, hT);
    k_attn<<<dim3(512), dim3(256), 0, stream>>>(x, gam, fKh, fKl, gQh, gQl, hT, out);
}